// Round 12
// baseline (155.230 us; speedup 1.0000x reference)
//
#include <hip/hip_runtime.h>

#define B 8
#define N 1024
#define E 10
#define GP 44                        // 4 emb rows packed in 44 floats (40 data + 4 pad)
#define EMB_FLOATS (256 * GP)        // 11264 floats per batch
#define EMB_F4 (EMB_FLOATS / 4)     // 2816 float4 per batch
#define BAR_PAD 32                   // 32 uints = 128 B between counters
#define NBLK 256                     // 8 batches x 32 tiles of 32 rows
#define TPB 32                       // blocks per batch (barrier domain)

typedef float f32x4 __attribute__((ext_vector_type(4)));

// ---------------------------------------------------------------------------
// Fence-free PER-BATCH barrier (32 blocks). All cross-block data moves via
// sc0|sc1 write-through stores and sc0|sc1 bypass loads, so no buffer_wbl2 /
// buffer_inv is needed. __syncthreads() drains vmcnt(0) for every wave before
// s_barrier, so all write-through stores are LLC-visible before the counter
// increment. Each counter on its own 128 B line; batches fully decoupled.
// ---------------------------------------------------------------------------
__device__ __forceinline__ void batch_barrier(unsigned* cnt) {
    __syncthreads();
    if (threadIdx.x == 0) {
        __hip_atomic_fetch_add(cnt, 1u, __ATOMIC_RELAXED, __HIP_MEMORY_SCOPE_AGENT);
        while (__hip_atomic_load(cnt, __ATOMIC_RELAXED, __HIP_MEMORY_SCOPE_AGENT) < TPB)
            __builtin_amdgcn_s_sleep(2);
    }
    __syncthreads();
    asm volatile("" ::: "memory");
}

__device__ __forceinline__ void store_llc(float* p, float v) {
    __hip_atomic_store((unsigned*)p, __float_as_uint(v),
                       __ATOMIC_RELAXED, __HIP_MEMORY_SCOPE_AGENT);
}
__device__ __forceinline__ float load_llc(const float* p) {
    unsigned u = __hip_atomic_load((const unsigned*)p,
                                   __ATOMIC_RELAXED, __HIP_MEMORY_SCOPE_AGENT);
    return __uint_as_float(u);
}

// ===========================================================================
// k8: k6 restructured for 64-VGPR friendliness (r7-r11: allocator pins 1024-
// thr kernels at 64 VGPR; R=4-in-registers unreachable).
//  - LDS reads become GROUP-BROADCAST: lane=(js 0..3, rs 0..15) owns rows
//    {2rs,2rs+1}, groups g=js*64+w*4+c. Per ds_read_b128 only 4 distinct
//    addresses (16-lane broadcast each) = 64 B/inst vs k6's 1 KB/inst ->
//    ~2.5x cheaper LDS pipe at same inst/FMA count.
//  - A no longer register-resident (frees 32 VGPR): streamed from L1/L2 per
//    iteration (64 B contiguous per lane per row across the c-loop); tile
//    warmed into L2 during phase-0 via coalesced dummy-sum (asm sink).
//  - Reduction: 2 shuffle rounds (js dims 16,32) + vred[16 waves] fan-in.
// Fallback: if k8 spills (localSizeBytes > 8), launch the proven k6.
// ===========================================================================

__global__ __launch_bounds__(1024, 4)
void k_fused8(
    const float* __restrict__ W, const float* __restrict__ features,
    const float* __restrict__ w_sel, const float* __restrict__ w_nbw,
    const float* __restrict__ w_ew, const float* __restrict__ A,
    const float* __restrict__ Wp, const float* __restrict__ w_reduc,
    const float* __restrict__ w_all, const float* __restrict__ w_act,
    float* eA, float* eB,
    float* __restrict__ emb_out, float* __restrict__ qv,
    float* __restrict__ qpart, unsigned* __restrict__ bars)
{
    __shared__ float4 EmS[EMB_F4];        // 45056 B (phase 0 overlays scratch)
    __shared__ float vredS[16 * 330];     // 21120 B: [w]*330 + r*10 + e
    __shared__ float WpS[E * E];
    __shared__ float gaSh[E], gactS[E];
    __shared__ float vS[32 * E], qS[32 * E], vS2[32 * E], qrow[32];
    __shared__ float qsumS;

    int bx = blockIdx.x, tid = threadIdx.x;
    int b = bx >> 5, tile = bx & 31;
    int i0 = tile * 32;
    int w = tid >> 6;     // wave 0..15
    int l = tid & 63;     // lane
    int js = l >> 4;      // j-slice 0..3
    int rs = l & 15;      // row-set: rows 2rs, 2rs+1
    unsigned* mybars = bars + b * BAR_PAD;

    // ---- A-tile L2 warm: 8 coalesced float4/thread, dummy-summed + sunk ----
    {
        const f32x4* Aw = (const f32x4*)(A + ((size_t)(b << 10) + i0) * N) + tid;
        f32x4 sink = {0.f, 0.f, 0.f, 0.f};
#pragma unroll
        for (int k = 0; k < 8; ++k) {
            f32x4 t = Aw[k * 1024];
            sink += t;
        }
        asm volatile("" :: "v"(sink.x), "v"(sink.y), "v"(sink.z), "v"(sink.w));
    }

    if (tid < E * E) WpS[tid] = Wp[tid];
    if (tid < E) {
        float sa = 0.f, sc = 0.f;
#pragma unroll
        for (int k = 0; k < E; ++k) {
            sa += w_reduc[k] * w_all[k * E + tid];
            sc += w_reduc[E + k] * w_act[k * E + tid];
        }
        gaSh[tid] = sa;
        gactS[tid] = sc;
    }

    // ---- phase 0: base + emb0 via relu-collapse, 32 cols/block (k6 exact) --
    float b_reg = 0.f;
    {
        float* redPt = (float*)&EmS[0];       // [32][129] transposed scratch
        float* redNt = redPt + 32 * 129;
        float* scol  = redNt + 32 * 129;      // [2][32]
        int c4 = (tid & 7) * 4;
        int rg = tid >> 3;
        const float* wp = W + ((size_t)b * N + rg * 8) * N + i0 + c4;
        float4 sp = {0.f, 0.f, 0.f, 0.f}, sn = {0.f, 0.f, 0.f, 0.f};
#pragma unroll
        for (int i = 0; i < 8; ++i) {
            float4 ww = *(const float4*)(wp + (size_t)i * N);
            sp.x += fmaxf(ww.x, 0.f); sn.x += fmaxf(-ww.x, 0.f);
            sp.y += fmaxf(ww.y, 0.f); sn.y += fmaxf(-ww.y, 0.f);
            sp.z += fmaxf(ww.z, 0.f); sn.z += fmaxf(-ww.z, 0.f);
            sp.w += fmaxf(ww.w, 0.f); sn.w += fmaxf(-ww.w, 0.f);
        }
        redPt[(c4 + 0) * 129 + rg] = sp.x; redNt[(c4 + 0) * 129 + rg] = sn.x;
        redPt[(c4 + 1) * 129 + rg] = sp.y; redNt[(c4 + 1) * 129 + rg] = sn.y;
        redPt[(c4 + 2) * 129 + rg] = sp.z; redNt[(c4 + 2) * 129 + rg] = sn.z;
        redPt[(c4 + 3) * 129 + rg] = sp.w; redNt[(c4 + 3) * 129 + rg] = sn.w;
        __syncthreads();
        if (tid < 64) {
            int cc = tid & 31;
            const float* rp = (tid < 32) ? redPt : redNt;
            float t = 0.f;
#pragma unroll 8
            for (int g = 0; g < 128; ++g) t += rp[cc * 129 + g];
            scol[(tid >> 5) * 32 + cc] = t;
        }
        __syncthreads();
        if (tid < 32 * E) {
            int cc = tid / E, f = tid % E;
            float spc = scol[cc], snc = scol[32 + cc];
            float acc = features[(b << 10) + i0 + cc] * w_sel[f];
#pragma unroll
            for (int e = 0; e < E; ++e) {
                float ce = w_ew[e];
                float se = (ce > 0.f) ? ce * spc : (-ce) * snc;
                acc += w_nbw[f * E + e] * se;
            }
            b_reg = acc;
            int row = i0 + cc;
            store_llc(&eA[(size_t)b * EMB_FLOATS + (row >> 2) * GP + (row & 3) * E + f],
                      fmaxf(acc, 0.f));
        }
    }
    batch_barrier(&mybars[0]);

    // per-lane A row pointers (const across iterations)
    const float* Ar0 = A + ((size_t)(b << 10) + i0 + 2 * rs) * N + 256 * js + 16 * w;
    const float* Ar1 = Ar0 + N;
    const float4* gp0 = EmS + (size_t)((js << 6) + (w << 2)) * (GP / 4);

    // ---- 4 remaining reference iterations ----
    float da = 0.f;
    for (int it = 0; it < 4; ++it) {
        const float* ein = (it & 1) ? (const float*)eB : (const float*)eA;
        float* eout = (it & 1) ? eA : eB;

        // stage whole-batch emb (k6 exact): 3 LLC-bypass float4/thread
        {
            const f32x4* src = (const f32x4*)ein + (size_t)b * EMB_F4;
            f32x4 t0, t1, t2 = {0.f, 0.f, 0.f, 0.f};
            asm volatile("global_load_dwordx4 %0, %1, off sc0 sc1"
                         : "=v"(t0) : "v"(src + tid) : "memory");
            asm volatile("global_load_dwordx4 %0, %1, off sc0 sc1"
                         : "=v"(t1) : "v"(src + tid + 1024) : "memory");
            if (tid < EMB_F4 - 2048)
                asm volatile("global_load_dwordx4 %0, %1, off sc0 sc1"
                             : "=v"(t2) : "v"(src + tid + 2048) : "memory");
            asm volatile("s_waitcnt vmcnt(0)" ::: "memory");
            __builtin_amdgcn_sched_barrier(0);
            ((f32x4*)EmS)[tid]        = t0;
            ((f32x4*)EmS)[tid + 1024] = t1;
            if (tid < EMB_F4 - 2048) ((f32x4*)EmS)[tid + 2048] = t2;
        }
        __syncthreads();

        float acc0[E], acc1[E];
#pragma unroll
        for (int e = 0; e < E; ++e) { acc0[e] = 0.f; acc1[e] = 0.f; }

#pragma unroll
        for (int c = 0; c < 4; ++c) {
            // group g = js*64 + w*4 + c; 4 distinct LDS addrs/inst (broadcast)
            const float4* gp = gp0 + (size_t)c * (GP / 4);
            float4 a0 = *(const float4*)(Ar0 + 4 * c);   // A[2rs][4g..4g+3]
            float4 a1 = *(const float4*)(Ar1 + 4 * c);   // A[2rs+1][..]
            {
                float ga[20];   // q0,q1 emb rows (floats 0..19)
                *(float4*)(ga + 0)  = gp[0];
                *(float4*)(ga + 4)  = gp[1];
                *(float4*)(ga + 8)  = gp[2];
                *(float4*)(ga + 12) = gp[3];
                *(float4*)(ga + 16) = gp[4];
#pragma unroll
                for (int e = 0; e < E; ++e) {
                    acc0[e] += a0.x * ga[e];
                    acc1[e] += a1.x * ga[e];
                }
#pragma unroll
                for (int e = 0; e < E; ++e) {
                    acc0[e] += a0.y * ga[10 + e];
                    acc1[e] += a1.y * ga[10 + e];
                }
            }
            {
                float gb[20];   // q2,q3 emb rows (floats 20..39)
                *(float4*)(gb + 0)  = gp[5];
                *(float4*)(gb + 4)  = gp[6];
                *(float4*)(gb + 8)  = gp[7];
                *(float4*)(gb + 12) = gp[8];
                *(float4*)(gb + 16) = gp[9];
#pragma unroll
                for (int e = 0; e < E; ++e) {
                    acc0[e] += a0.z * gb[e];
                    acc1[e] += a1.z * gb[e];
                }
#pragma unroll
                for (int e = 0; e < E; ++e) {
                    acc0[e] += a0.w * gb[10 + e];
                    acc1[e] += a1.w * gb[10 + e];
                }
            }
        }

        // reduce over js (lanes 16,32 apart); lanes js==0 hold wave partials
#pragma unroll
        for (int mask = 16; mask <= 32; mask <<= 1)
#pragma unroll
            for (int e = 0; e < E; ++e) {
                acc0[e] += __shfl_xor(acc0[e], mask, 64);
                acc1[e] += __shfl_xor(acc1[e], mask, 64);
            }
        if (l < 16) {
#pragma unroll
            for (int e = 0; e < E; ++e) {
                vredS[w * 330 + (2 * rs) * E + e]     = acc0[e];
                vredS[w * 330 + (2 * rs + 1) * E + e] = acc1[e];
            }
        }
        __syncthreads();

        // fan-in over 16 waves: thread (r,e) reads stride-330 (consecutive tid)
        if (tid < 32 * E) {
            float t = 0.f;
#pragma unroll
            for (int ww = 0; ww < 16; ++ww) t += vredS[ww * 330 + tid];
            vS2[tid] = t;
        }
        __syncthreads();

        if (tid < 32 * E) {
            int r = tid / E, f = tid % E;
            float d = 0.f;
#pragma unroll
            for (int e = 0; e < E; ++e) d += vS2[r * E + e] * WpS[f * E + e];
            float r_out = fmaxf(b_reg + d, 0.f);
            if (it < 3) {
                int grow = i0 + r;
                store_llc(&eout[(size_t)b * EMB_FLOATS + (grow >> 2) * GP + (grow & 3) * E + f],
                          r_out);
            } else {
                size_t gi = (size_t)((b << 10) + i0 + r);
                emb_out[gi * E + f] = r_out;
                vS[tid] = r_out * gactS[f];
                qS[tid] = r_out * gaSh[f];
            }
        }
        if (it < 3) batch_barrier(&mybars[(1 + it) * B * BAR_PAD]);
    }

    // ---- q epilogue (k6 exact) ----
    __syncthreads();
    if (tid < 32) {
        float dg = 0.f;
#pragma unroll
        for (int f = 0; f < E; ++f) {
            da += vS[tid * E + f];
            dg += qS[tid * E + f];
        }
        qrow[tid] = dg;
    }
    __syncthreads();
    if (tid == 0) {
        float t = 0.f;
#pragma unroll
        for (int r = 0; r < 32; ++r) t += qrow[r];
        store_llc(&qpart[bx], t);
    }
    batch_barrier(&mybars[4 * B * BAR_PAD]);

    if (tid < 32) {
        float t = load_llc(&qpart[(b << 5) + tid]);
#pragma unroll
        for (int mask = 1; mask < 32; mask <<= 1)
            t += __shfl_xor(t, mask, 32);
        if (tid == 0) qsumS = t;
    }
    __syncthreads();
    if (tid < 32) qv[(b << 10) + i0 + tid] = da + qsumS;
}

// --------------------------- k6 (round-6 exact, fallback) -------------------
__global__ __launch_bounds__(1024, 4)
void k_fused6(
    const float* __restrict__ W, const float* __restrict__ features,
    const float* __restrict__ w_sel, const float* __restrict__ w_nbw,
    const float* __restrict__ w_ew, const float* __restrict__ A,
    const float* __restrict__ Wp, const float* __restrict__ w_reduc,
    const float* __restrict__ w_all, const float* __restrict__ w_act,
    float* eA, float* eB,
    float* __restrict__ emb_out, float* __restrict__ qv,
    float* __restrict__ qpart, unsigned* __restrict__ bars)
{
    __shared__ float4 EmS[EMB_F4];
    __shared__ float vred[16][9][2 * E];
    __shared__ float WpS[E * E];
    __shared__ float gaS[E], gactS[E];
    __shared__ float vS[32 * E], qS[32 * E], qrow[32];
    __shared__ float qsumS;

    int bx = blockIdx.x, tid = threadIdx.x;
    int b = bx >> 5, tile = bx & 31;
    int i0 = tile * 32;
    int m = tid >> 6;
    int s = tid & 63;
    unsigned* mybars = bars + b * BAR_PAD;

    float Arf[2][4][4];
    {
        const float* Ab = A + ((size_t)(b * N) + i0 + m) * N + 4 * s;
#pragma unroll
        for (int k = 0; k < 2; ++k)
#pragma unroll
            for (int c = 0; c < 4; ++c) {
                float4 t = *(const float4*)(Ab + (size_t)(16 * k) * N + 256 * c);
                Arf[k][c][0] = t.x; Arf[k][c][1] = t.y;
                Arf[k][c][2] = t.z; Arf[k][c][3] = t.w;
            }
    }

    if (tid < E * E) WpS[tid] = Wp[tid];
    if (tid < E) {
        float sa = 0.f, sc = 0.f;
#pragma unroll
        for (int k = 0; k < E; ++k) {
            sa += w_reduc[k] * w_all[k * E + tid];
            sc += w_reduc[E + k] * w_act[k * E + tid];
        }
        gaS[tid] = sa;
        gactS[tid] = sc;
    }

    float b_reg = 0.f;
    {
        float* redPt = (float*)&EmS[0];
        float* redNt = redPt + 32 * 129;
        float* scol  = redNt + 32 * 129;
        int c4 = (tid & 7) * 4;
        int rg = tid >> 3;
        const float* wp = W + ((size_t)b * N + rg * 8) * N + i0 + c4;
        float4 sp = {0.f, 0.f, 0.f, 0.f}, sn = {0.f, 0.f, 0.f, 0.f};
#pragma unroll
        for (int i = 0; i < 8; ++i) {
            float4 ww = *(const float4*)(wp + (size_t)i * N);
            sp.x += fmaxf(ww.x, 0.f); sn.x += fmaxf(-ww.x, 0.f);
            sp.y += fmaxf(ww.y, 0.f); sn.y += fmaxf(-ww.y, 0.f);
            sp.z += fmaxf(ww.z, 0.f); sn.z += fmaxf(-ww.z, 0.f);
            sp.w += fmaxf(ww.w, 0.f); sn.w += fmaxf(-ww.w, 0.f);
        }
        redPt[(c4 + 0) * 129 + rg] = sp.x; redNt[(c4 + 0) * 129 + rg] = sn.x;
        redPt[(c4 + 1) * 129 + rg] = sp.y; redNt[(c4 + 1) * 129 + rg] = sn.y;
        redPt[(c4 + 2) * 129 + rg] = sp.z; redNt[(c4 + 2) * 129 + rg] = sn.z;
        redPt[(c4 + 3) * 129 + rg] = sp.w; redNt[(c4 + 3) * 129 + rg] = sn.w;
        __syncthreads();
        if (tid < 64) {
            int cc = tid & 31;
            const float* rp = (tid < 32) ? redPt : redNt;
            float t = 0.f;
#pragma unroll 8
            for (int g = 0; g < 128; ++g) t += rp[cc * 129 + g];
            scol[(tid >> 5) * 32 + cc] = t;
        }
        __syncthreads();
        if (tid < 32 * E) {
            int cc = tid / E, f = tid % E;
            float spc = scol[cc], snc = scol[32 + cc];
            float acc = features[(b << 10) + i0 + cc] * w_sel[f];
#pragma unroll
            for (int e = 0; e < E; ++e) {
                float ce = w_ew[e];
                float se = (ce > 0.f) ? ce * spc : (-ce) * snc;
                acc += w_nbw[f * E + e] * se;
            }
            b_reg = acc;
            int row = i0 + cc;
            store_llc(&eA[(size_t)b * EMB_FLOATS + (row >> 2) * GP + (row & 3) * E + f],
                      fmaxf(acc, 0.f));
        }
    }
    batch_barrier(&mybars[0]);

    float da = 0.f;
    for (int it = 0; it < 4; ++it) {
        const float* ein = (it & 1) ? (const float*)eB : (const float*)eA;
        float* eout = (it & 1) ? eA : eB;

        {
            const f32x4* src = (const f32x4*)ein + (size_t)b * EMB_F4;
            f32x4 t0, t1, t2 = {0.f, 0.f, 0.f, 0.f};
            asm volatile("global_load_dwordx4 %0, %1, off sc0 sc1"
                         : "=v"(t0) : "v"(src + tid) : "memory");
            asm volatile("global_load_dwordx4 %0, %1, off sc0 sc1"
                         : "=v"(t1) : "v"(src + tid + 1024) : "memory");
            if (tid < EMB_F4 - 2048)
                asm volatile("global_load_dwordx4 %0, %1, off sc0 sc1"
                             : "=v"(t2) : "v"(src + tid + 2048) : "memory");
            asm volatile("s_waitcnt vmcnt(0)" ::: "memory");
            __builtin_amdgcn_sched_barrier(0);
            ((f32x4*)EmS)[tid]        = t0;
            ((f32x4*)EmS)[tid + 1024] = t1;
            if (tid < EMB_F4 - 2048) ((f32x4*)EmS)[tid + 2048] = t2;
        }
        __syncthreads();

        float acc[2][E];
#pragma unroll
        for (int k = 0; k < 2; ++k)
#pragma unroll
            for (int e = 0; e < E; ++e) acc[k][e] = 0.f;

#pragma unroll
        for (int c = 0; c < 4; ++c) {
            float4 g4[10];
            const float4* gp = EmS + (size_t)(s + 64 * c) * (GP / 4);
#pragma unroll
            for (int t = 0; t < 10; ++t) g4[t] = gp[t];
            const float* g40 = (const float*)g4;
#pragma unroll
            for (int q = 0; q < 4; ++q)
#pragma unroll
                for (int k = 0; k < 2; ++k) {
                    float a = Arf[k][c][q];
#pragma unroll
                    for (int e = 0; e < E; ++e)
                        acc[k][e] += a * g40[q * E + e];
                }
        }

#pragma unroll
        for (int mask = 1; mask <= 4; mask <<= 1)
#pragma unroll
            for (int k = 0; k < 2; ++k)
#pragma unroll
                for (int e = 0; e < E; ++e)
                    acc[k][e] += __shfl_xor(acc[k][e], mask, 64);
        if ((s & 7) == 0)
#pragma unroll
            for (int k = 0; k < 2; ++k)
#pragma unroll
                for (int e = 0; e < E; ++e)
                    vred[m][s >> 3][k * E + e] = acc[k][e];
        __syncthreads();

        if (tid < 32 * E) {
            int r = tid / E, f = tid % E;
            int mm = r & 15, kk = r >> 4;
            float v[E];
#pragma unroll
            for (int e = 0; e < E; ++e) {
                float t = 0.f;
#pragma unroll
                for (int g = 0; g < 8; ++g) t += vred[mm][g][kk * E + e];
                v[e] = t;
            }
            float d = 0.f;
#pragma unroll
            for (int e = 0; e < E; ++e) d += v[e] * WpS[f * E + e];
            float r_out = fmaxf(b_reg + d, 0.f);
            if (it < 3) {
                int grow = i0 + r;
                store_llc(&eout[(size_t)b * EMB_FLOATS + (grow >> 2) * GP + (grow & 3) * E + f],
                          r_out);
            } else {
                size_t gi = (size_t)((b << 10) + i0 + r);
                emb_out[gi * E + f] = r_out;
                vS[tid] = r_out * gactS[f];
                qS[tid] = r_out * gaS[f];
            }
        }
        if (it < 3) batch_barrier(&mybars[(1 + it) * B * BAR_PAD]);
    }

    __syncthreads();
    if (tid < 32) {
        float dg = 0.f;
#pragma unroll
        for (int f = 0; f < E; ++f) {
            da += vS[tid * E + f];
            dg += qS[tid * E + f];
        }
        qrow[tid] = dg;
    }
    __syncthreads();
    if (tid == 0) {
        float t = 0.f;
#pragma unroll
        for (int r = 0; r < 32; ++r) t += qrow[r];
        store_llc(&qpart[bx], t);
    }
    batch_barrier(&mybars[4 * B * BAR_PAD]);

    if (tid < 32) {
        float t = load_llc(&qpart[(b << 5) + tid]);
#pragma unroll
        for (int mask = 1; mask < 32; mask <<= 1)
            t += __shfl_xor(t, mask, 32);
        if (tid == 0) qsumS = t;
    }
    __syncthreads();
    if (tid < 32) qv[(b << 10) + i0 + tid] = da + qsumS;
}

extern "C" void kernel_launch(void* const* d_in, const int* in_sizes, int n_in,
                              void* d_out, int out_size, void* d_ws, size_t ws_size,
                              hipStream_t stream) {
    const float* features  = (const float*)d_in[0];
    const float* W         = (const float*)d_in[1];
    const float* adjacency = (const float*)d_in[2];
    const float* w_sel     = (const float*)d_in[3];
    const float* w_pri     = (const float*)d_in[4];
    const float* w_nbw     = (const float*)d_in[5];
    const float* w_ew      = (const float*)d_in[6];
    const float* w_reduc   = (const float*)d_in[7];
    const float* w_all     = (const float*)d_in[8];
    const float* w_act     = (const float*)d_in[9];

    float* out     = (float*)d_out;
    float* qv      = out;              // B*N
    float* emb_out = out + B * N;      // B*N*E

    float* ws      = (float*)d_ws;
    float* eA      = ws;                               // B*EMB_FLOATS
    float* eB      = eA + (size_t)B * EMB_FLOATS;
    float* qpart   = eB + (size_t)B * EMB_FLOATS;      // 256 floats
    unsigned* bars = (unsigned*)(qpart + NBLK);        // 5 stages x 8 batches x 128B

    // k8 unless it spilled (localSizeBytes>8) — then proven k6.
    static int use8 = -1;
    if (use8 < 0) {
        hipFuncAttributes fa{};
        use8 = 0;
        if (hipFuncGetAttributes(&fa, (const void*)k_fused8) == hipSuccess &&
            fa.localSizeBytes <= 8)
            use8 = 1;
    }

    hipMemsetAsync(bars, 0, 5 * B * BAR_PAD * sizeof(unsigned), stream);
    if (use8)
        k_fused8<<<NBLK, 1024, 0, stream>>>(W, features, w_sel, w_nbw, w_ew,
                                            adjacency, w_pri, w_reduc, w_all,
                                            w_act, eA, eB, emb_out, qv, qpart,
                                            bars);
    else
        k_fused6<<<NBLK, 1024, 0, stream>>>(W, features, w_sel, w_nbw, w_ew,
                                            adjacency, w_pri, w_reduc, w_all,
                                            w_act, eA, eB, emb_out, qv, qpart,
                                            bars);
}

// Round 13
// 146.055 us; speedup vs baseline: 1.0628x; 1.0628x over previous
//
#include <hip/hip_runtime.h>

#define B 8
#define N 1024
#define E 10
#define GP 44                        // 4 emb rows packed in 44 floats (40 data + 4 pad)
#define EMB_FLOATS (256 * GP)        // 11264 floats per batch
#define EMB_F4 (EMB_FLOATS / 4)      // 2816 float4 per batch
#define BAR_PAD 32                   // 32 uints = 128 B between counters
#define NBLK 256                     // 8 batches x 32 tiles of 32 rows
#define TPB 32                       // blocks per batch (barrier domain)

typedef float f32x4 __attribute__((ext_vector_type(4)));

// ---------------------------------------------------------------------------
// Fence-free PER-BATCH barrier (32 blocks). All cross-block data moves via
// sc0|sc1 write-through stores and sc0|sc1 bypass loads, so no buffer_wbl2 /
// buffer_inv is needed. __syncthreads() drains vmcnt(0) for every wave before
// s_barrier, so all write-through stores are LLC-visible before the counter
// increment. Each counter on its own 128 B line; batches fully decoupled.
// ---------------------------------------------------------------------------
__device__ __forceinline__ void batch_barrier(unsigned* cnt) {
    __syncthreads();
    if (threadIdx.x == 0) {
        __hip_atomic_fetch_add(cnt, 1u, __ATOMIC_RELAXED, __HIP_MEMORY_SCOPE_AGENT);
        while (__hip_atomic_load(cnt, __ATOMIC_RELAXED, __HIP_MEMORY_SCOPE_AGENT) < TPB)
            __builtin_amdgcn_s_sleep(2);
    }
    __syncthreads();
    asm volatile("" ::: "memory");
}

__device__ __forceinline__ void store_llc(float* p, float v) {
    __hip_atomic_store((unsigned*)p, __float_as_uint(v),
                       __ATOMIC_RELAXED, __HIP_MEMORY_SCOPE_AGENT);
}
__device__ __forceinline__ float load_llc(const float* p) {
    unsigned u = __hip_atomic_load((const unsigned*)p,
                                   __ATOMIC_RELAXED, __HIP_MEMORY_SCOPE_AGENT);
    return __uint_as_float(u);
}

// DPP row_shr accumulate: x += value from lane (i - n) within the 16-lane row
// (bound_ctrl=1 -> 0 past row edge). After n=1,2,4 lane 7 of each 8-lane
// group holds the 8-lane sum. VALU pipe — replaces ds_swizzle shuffles.
#define DPP_ACC(x, ctrl)                                                      \
    x += __int_as_float(__builtin_amdgcn_update_dpp(                          \
        0, __float_as_int(x), (ctrl), 0xf, 0xf, true))

// ===========================================================================
// k9 = k6 (proven 52us structure) with ONE change: the 8-lane reduction uses
// DPP row_shr adds (VALU) instead of 60 __shfl_xor (ds_swizzle -> LDS pipe).
// k6's iteration LDS pipe carried 40 ds_read_b128 (~3.2us/CU) PLUS ~2.3us of
// shuffle traffic per iteration; DPP moves the latter to the idle VALU.
// r12's k8 lessons reverted: A stays register-resident (k8 re-fetched +42 MB
// HBM), per-lane LDS reads keep k6's conflict-free layout (k8's "broadcast"
// groups were 11264 B apart = same bank -> 2.8M conflicts).
// ===========================================================================
__global__ __launch_bounds__(1024, 4)
void k_fused9(
    const float* __restrict__ W, const float* __restrict__ features,
    const float* __restrict__ w_sel, const float* __restrict__ w_nbw,
    const float* __restrict__ w_ew, const float* __restrict__ A,
    const float* __restrict__ Wp, const float* __restrict__ w_reduc,
    const float* __restrict__ w_all, const float* __restrict__ w_act,
    float* eA, float* eB,
    float* __restrict__ emb_out, float* __restrict__ qv,
    float* __restrict__ qpart, unsigned* __restrict__ bars)
{
    __shared__ float4 EmS[EMB_F4];        // 45056 B (phase 0 overlays scratch)
    __shared__ float vred[16][9][2 * E];  // padded: stride 180 words (20 mod 32)
    __shared__ float WpS[E * E];
    __shared__ float gaS[E], gactS[E];
    __shared__ float vS[32 * E], qS[32 * E], qrow[32];
    __shared__ float qsumS;

    int bx = blockIdx.x, tid = threadIdx.x;
    int b = bx >> 5, tile = bx & 31;
    int i0 = tile * 32;
    int m = tid >> 6;     // wave 0..15: rows i0 + m + 16k
    int s = tid & 63;     // lane: cols 4s + q + 256c
    unsigned* mybars = bars + b * BAR_PAD;

    // ---- A tile (32 rows) -> registers, ONCE ----
    float Arf[2][4][4];
    {
        const float* Ab = A + ((size_t)(b * N) + i0 + m) * N + 4 * s;
#pragma unroll
        for (int k = 0; k < 2; ++k)
#pragma unroll
            for (int c = 0; c < 4; ++c) {
                float4 t = *(const float4*)(Ab + (size_t)(16 * k) * N + 256 * c);
                Arf[k][c][0] = t.x; Arf[k][c][1] = t.y;
                Arf[k][c][2] = t.z; Arf[k][c][3] = t.w;
            }
    }

    if (tid < E * E) WpS[tid] = Wp[tid];
    if (tid < E) {
        float sa = 0.f, sc = 0.f;
#pragma unroll
        for (int k = 0; k < E; ++k) {
            sa += w_reduc[k] * w_all[k * E + tid];
            sc += w_reduc[E + k] * w_act[k * E + tid];
        }
        gaS[tid] = sa;
        gactS[tid] = sc;
    }

    // ---- phase 0: base + emb0 via relu-collapse, 32 cols/block ----
    float b_reg = 0.f;
    {
        float* redPt = (float*)&EmS[0];       // [32][129] transposed scratch
        float* redNt = redPt + 32 * 129;
        float* scol  = redNt + 32 * 129;      // [2][32]
        int c4 = (tid & 7) * 4;
        int rg = tid >> 3;
        const float* wp = W + ((size_t)b * N + rg * 8) * N + i0 + c4;
        float4 sp = {0.f, 0.f, 0.f, 0.f}, sn = {0.f, 0.f, 0.f, 0.f};
#pragma unroll
        for (int i = 0; i < 8; ++i) {
            float4 ww = *(const float4*)(wp + (size_t)i * N);
            sp.x += fmaxf(ww.x, 0.f); sn.x += fmaxf(-ww.x, 0.f);
            sp.y += fmaxf(ww.y, 0.f); sn.y += fmaxf(-ww.y, 0.f);
            sp.z += fmaxf(ww.z, 0.f); sn.z += fmaxf(-ww.z, 0.f);
            sp.w += fmaxf(ww.w, 0.f); sn.w += fmaxf(-ww.w, 0.f);
        }
        redPt[(c4 + 0) * 129 + rg] = sp.x; redNt[(c4 + 0) * 129 + rg] = sn.x;
        redPt[(c4 + 1) * 129 + rg] = sp.y; redNt[(c4 + 1) * 129 + rg] = sn.y;
        redPt[(c4 + 2) * 129 + rg] = sp.z; redNt[(c4 + 2) * 129 + rg] = sn.z;
        redPt[(c4 + 3) * 129 + rg] = sp.w; redNt[(c4 + 3) * 129 + rg] = sn.w;
        __syncthreads();
        if (tid < 64) {
            int cc = tid & 31;
            const float* rp = (tid < 32) ? redPt : redNt;
            float t = 0.f;
#pragma unroll 8
            for (int g = 0; g < 128; ++g) t += rp[cc * 129 + g];
            scol[(tid >> 5) * 32 + cc] = t;
        }
        __syncthreads();
        if (tid < 32 * E) {
            int cc = tid / E, f = tid % E;
            float spc = scol[cc], snc = scol[32 + cc];
            float acc = features[(b << 10) + i0 + cc] * w_sel[f];
#pragma unroll
            for (int e = 0; e < E; ++e) {
                float ce = w_ew[e];
                float se = (ce > 0.f) ? ce * spc : (-ce) * snc;
                acc += w_nbw[f * E + e] * se;
            }
            b_reg = acc;
            int row = i0 + cc;
            store_llc(&eA[(size_t)b * EMB_FLOATS + (row >> 2) * GP + (row & 3) * E + f],
                      fmaxf(acc, 0.f));
        }
    }
    batch_barrier(&mybars[0]);

    // ---- 4 remaining reference iterations, A tile register-resident ----
    float da = 0.f;
    for (int it = 0; it < 4; ++it) {
        const float* ein = (it & 1) ? (const float*)eB : (const float*)eA;
        float* eout = (it & 1) ? eA : eB;

        // stage whole-batch emb: 3 LLC-bypass float4 loads/thread, ds_writes
        {
            const f32x4* src = (const f32x4*)ein + (size_t)b * EMB_F4;
            f32x4 t0, t1, t2 = {0.f, 0.f, 0.f, 0.f};
            asm volatile("global_load_dwordx4 %0, %1, off sc0 sc1"
                         : "=v"(t0) : "v"(src + tid) : "memory");
            asm volatile("global_load_dwordx4 %0, %1, off sc0 sc1"
                         : "=v"(t1) : "v"(src + tid + 1024) : "memory");
            if (tid < EMB_F4 - 2048)
                asm volatile("global_load_dwordx4 %0, %1, off sc0 sc1"
                             : "=v"(t2) : "v"(src + tid + 2048) : "memory");
            asm volatile("s_waitcnt vmcnt(0)" ::: "memory");
            __builtin_amdgcn_sched_barrier(0);
            ((f32x4*)EmS)[tid]        = t0;
            ((f32x4*)EmS)[tid + 1024] = t1;
            if (tid < EMB_F4 - 2048) ((f32x4*)EmS)[tid + 2048] = t2;
        }
        __syncthreads();

        float acc[2][E];
#pragma unroll
        for (int k = 0; k < 2; ++k)
#pragma unroll
            for (int e = 0; e < E; ++e) acc[k][e] = 0.f;

#pragma unroll
        for (int c = 0; c < 4; ++c) {
            float4 g4[10];
            const float4* gp = EmS + (size_t)(s + 64 * c) * (GP / 4);
#pragma unroll
            for (int t = 0; t < 10; ++t) g4[t] = gp[t];
            const float* g40 = (const float*)g4;
#pragma unroll
            for (int q = 0; q < 4; ++q)
#pragma unroll
                for (int k = 0; k < 2; ++k) {
                    float a = Arf[k][c][q];
#pragma unroll
                    for (int e = 0; e < E; ++e)
                        acc[k][e] += a * g40[q * E + e];
                }
        }

        // 8-lane group reduction via DPP row_shr (VALU pipe, zero LDS):
        // lane (s&7)==7 ends with the group sum.
#pragma unroll
        for (int k = 0; k < 2; ++k)
#pragma unroll
            for (int e = 0; e < E; ++e) {
                float x = acc[k][e];
                DPP_ACC(x, 0x111);   // row_shr:1
                DPP_ACC(x, 0x112);   // row_shr:2
                DPP_ACC(x, 0x114);   // row_shr:4
                acc[k][e] = x;
            }
        if ((s & 7) == 7)
#pragma unroll
            for (int k = 0; k < 2; ++k)
#pragma unroll
                for (int e = 0; e < E; ++e)
                    vred[m][s >> 3][k * E + e] = acc[k][e];
        __syncthreads();

        if (tid < 32 * E) {
            int r = tid / E, f = tid % E;
            int mm = r & 15, kk = r >> 4;
            float v[E];
#pragma unroll
            for (int e = 0; e < E; ++e) {
                float t = 0.f;
#pragma unroll
                for (int g = 0; g < 8; ++g) t += vred[mm][g][kk * E + e];
                v[e] = t;
            }
            float d = 0.f;
#pragma unroll
            for (int e = 0; e < E; ++e) d += v[e] * WpS[f * E + e];
            float r_out = fmaxf(b_reg + d, 0.f);
            if (it < 3) {
                int grow = i0 + r;
                store_llc(&eout[(size_t)b * EMB_FLOATS + (grow >> 2) * GP + (grow & 3) * E + f],
                          r_out);
            } else {
                size_t gi = (size_t)((b << 10) + i0 + r);
                emb_out[gi * E + f] = r_out;
                vS[tid] = r_out * gactS[f];
                qS[tid] = r_out * gaS[f];
            }
        }
        if (it < 3) batch_barrier(&mybars[(1 + it) * B * BAR_PAD]);
    }

    // ---- q epilogue: per-tile partials, one barrier, deterministic sum ----
    __syncthreads();
    if (tid < 32) {
        float dg = 0.f;
#pragma unroll
        for (int f = 0; f < E; ++f) {
            da += vS[tid * E + f];
            dg += qS[tid * E + f];
        }
        qrow[tid] = dg;
    }
    __syncthreads();
    if (tid == 0) {
        float t = 0.f;
#pragma unroll
        for (int r = 0; r < 32; ++r) t += qrow[r];
        store_llc(&qpart[bx], t);
    }
    batch_barrier(&mybars[4 * B * BAR_PAD]);

    if (tid < 32) {
        float t = load_llc(&qpart[(b << 5) + tid]);
#pragma unroll
        for (int mask = 1; mask < 32; mask <<= 1)
            t += __shfl_xor(t, mask, 32);
        if (tid == 0) qsumS = t;
    }
    __syncthreads();
    if (tid < 32) qv[(b << 10) + i0 + tid] = da + qsumS;
}

extern "C" void kernel_launch(void* const* d_in, const int* in_sizes, int n_in,
                              void* d_out, int out_size, void* d_ws, size_t ws_size,
                              hipStream_t stream) {
    const float* features  = (const float*)d_in[0];
    const float* W         = (const float*)d_in[1];
    const float* adjacency = (const float*)d_in[2];
    const float* w_sel     = (const float*)d_in[3];
    const float* w_pri     = (const float*)d_in[4];
    const float* w_nbw     = (const float*)d_in[5];
    const float* w_ew      = (const float*)d_in[6];
    const float* w_reduc   = (const float*)d_in[7];
    const float* w_all     = (const float*)d_in[8];
    const float* w_act     = (const float*)d_in[9];

    float* out     = (float*)d_out;
    float* qv      = out;              // B*N
    float* emb_out = out + B * N;      // B*N*E

    float* ws      = (float*)d_ws;
    float* eA      = ws;                               // B*EMB_FLOATS
    float* eB      = eA + (size_t)B * EMB_FLOATS;
    float* qpart   = eB + (size_t)B * EMB_FLOATS;      // 256 floats
    unsigned* bars = (unsigned*)(qpart + NBLK);        // 5 stages x 8 batches x 128B

    hipMemsetAsync(bars, 0, 5 * B * BAR_PAD * sizeof(unsigned), stream);
    k_fused9<<<NBLK, 1024, 0, stream>>>(W, features, w_sel, w_nbw, w_ew,
                                        adjacency, w_pri, w_reduc, w_all,
                                        w_act, eA, eB, emb_out, qv, qpart,
                                        bars);
}

// Round 14
// 145.122 us; speedup vs baseline: 1.0696x; 1.0064x over previous
//
#include <hip/hip_runtime.h>

#define B 8
#define N 1024
#define E 10
#define GP 44                        // 4 emb rows packed in 44 floats (40 data + 4 pad)
#define EMB_FLOATS (256 * GP)        // 11264 floats per batch
#define EMB_F4 (EMB_FLOATS / 4)      // 2816 float4 per batch
#define BAR_PAD 32                   // 32 uints = 128 B between counters
#define NBLK 256                     // 8 batches x 32 tiles of 32 rows
#define TPB 32                       // blocks per batch (barrier domain)

typedef float f32x4 __attribute__((ext_vector_type(4)));

// ---------------------------------------------------------------------------
// Fence-free PER-BATCH barrier (32 blocks). All cross-block data moves via
// sc0|sc1 write-through stores and sc0|sc1 bypass loads, so no buffer_wbl2 /
// buffer_inv is needed. __syncthreads() drains vmcnt(0) for every wave before
// s_barrier, so all write-through stores are LLC-visible before the counter
// increment. Each counter on its own 128 B line; batches fully decoupled.
// ---------------------------------------------------------------------------
__device__ __forceinline__ void batch_barrier(unsigned* cnt) {
    __syncthreads();
    if (threadIdx.x == 0) {
        __hip_atomic_fetch_add(cnt, 1u, __ATOMIC_RELAXED, __HIP_MEMORY_SCOPE_AGENT);
        while (__hip_atomic_load(cnt, __ATOMIC_RELAXED, __HIP_MEMORY_SCOPE_AGENT) < TPB)
            __builtin_amdgcn_s_sleep(2);
    }
    __syncthreads();
    asm volatile("" ::: "memory");
}

__device__ __forceinline__ void store_llc(float* p, float v) {
    __hip_atomic_store((unsigned*)p, __float_as_uint(v),
                       __ATOMIC_RELAXED, __HIP_MEMORY_SCOPE_AGENT);
}
__device__ __forceinline__ float load_llc(const float* p) {
    unsigned u = __hip_atomic_load((const unsigned*)p,
                                   __ATOMIC_RELAXED, __HIP_MEMORY_SCOPE_AGENT);
    return __uint_as_float(u);
}

// DPP accumulate (VALU pipe). old=0 => lanes outside row_mask / shifted past
// the row edge contribute 0.
#define DPP_ADD(x, ctrl, rmask)                                               \
    x += __int_as_float(__builtin_amdgcn_update_dpp(                          \
        0, __float_as_int(x), (ctrl), (rmask), 0xf, true))

// Full 64-lane sum: row_shr 1,2,4,8 (row sums at lanes 15/31/47/63), then
// row_bcast15 (lane15->row1, lane47->row3; write rows 1,3) and row_bcast31
// (lane31->rows 2,3). Lane 63 ends with the total.
#define DPP_REDUCE64(x)                                                       \
    do {                                                                      \
        DPP_ADD(x, 0x111, 0xf);  /* row_shr:1  */                             \
        DPP_ADD(x, 0x112, 0xf);  /* row_shr:2  */                             \
        DPP_ADD(x, 0x114, 0xf);  /* row_shr:4  */                             \
        DPP_ADD(x, 0x118, 0xf);  /* row_shr:8  */                             \
        DPP_ADD(x, 0x142, 0xa);  /* row_bcast15 -> rows 1,3 */                \
        DPP_ADD(x, 0x143, 0xc);  /* row_bcast31 -> rows 2,3 */                \
    } while (0)

// ===========================================================================
// k10 = k9 with the reduction finished IN-REGISTER: full 64-lane DPP sum per
// (k,e) value (wave m's lanes cover all 1024 j for its 2 rows), so lane 63
// holds the complete v[row][e]. Removes the vred round-trip that cost
// ~1.7us/iter on the LDS pipe (20 ds_write x16 waves + 80 ds_read x5 waves)
// -> 5 packed ds_write_b128 by lane 63 + 10 broadcast reads per epilogue
// thread. Extra 3 DPP steps/value run on the ~80%-idle VALU.
// Everything else identical to k9 (proven: 64 VGPR no-spill, conflicts 0).
// ===========================================================================
__global__ __launch_bounds__(1024, 4)
void k_fused10(
    const float* __restrict__ W, const float* __restrict__ features,
    const float* __restrict__ w_sel, const float* __restrict__ w_nbw,
    const float* __restrict__ w_ew, const float* __restrict__ A,
    const float* __restrict__ Wp, const float* __restrict__ w_reduc,
    const float* __restrict__ w_all, const float* __restrict__ w_act,
    float* eA, float* eB,
    float* __restrict__ emb_out, float* __restrict__ qv,
    float* __restrict__ qpart, unsigned* __restrict__ bars)
{
    __shared__ float4 EmS[EMB_F4];        // 45056 B (phase 0 overlays scratch)
    __shared__ float vred[16][24];        // row stride 96 B (24 mod 32 banks)
    __shared__ float WpS[E * E];
    __shared__ float gaS[E], gactS[E];
    __shared__ float vS[32 * E], qS[32 * E], qrow[32];
    __shared__ float qsumS;

    int bx = blockIdx.x, tid = threadIdx.x;
    int b = bx >> 5, tile = bx & 31;
    int i0 = tile * 32;
    int m = tid >> 6;     // wave 0..15: rows i0 + m + 16k
    int s = tid & 63;     // lane: cols 4s + q + 256c
    unsigned* mybars = bars + b * BAR_PAD;

    // ---- A tile (32 rows) -> registers, ONCE ----
    float Arf[2][4][4];
    {
        const float* Ab = A + ((size_t)(b * N) + i0 + m) * N + 4 * s;
#pragma unroll
        for (int k = 0; k < 2; ++k)
#pragma unroll
            for (int c = 0; c < 4; ++c) {
                float4 t = *(const float4*)(Ab + (size_t)(16 * k) * N + 256 * c);
                Arf[k][c][0] = t.x; Arf[k][c][1] = t.y;
                Arf[k][c][2] = t.z; Arf[k][c][3] = t.w;
            }
    }

    if (tid < E * E) WpS[tid] = Wp[tid];
    if (tid < E) {
        float sa = 0.f, sc = 0.f;
#pragma unroll
        for (int k = 0; k < E; ++k) {
            sa += w_reduc[k] * w_all[k * E + tid];
            sc += w_reduc[E + k] * w_act[k * E + tid];
        }
        gaS[tid] = sa;
        gactS[tid] = sc;
    }

    // ---- phase 0: base + emb0 via relu-collapse, 32 cols/block ----
    float b_reg = 0.f;
    {
        float* redPt = (float*)&EmS[0];       // [32][129] transposed scratch
        float* redNt = redPt + 32 * 129;
        float* scol  = redNt + 32 * 129;      // [2][32]
        int c4 = (tid & 7) * 4;
        int rg = tid >> 3;
        const float* wp = W + ((size_t)b * N + rg * 8) * N + i0 + c4;
        float4 sp = {0.f, 0.f, 0.f, 0.f}, sn = {0.f, 0.f, 0.f, 0.f};
#pragma unroll
        for (int i = 0; i < 8; ++i) {
            float4 ww = *(const float4*)(wp + (size_t)i * N);
            sp.x += fmaxf(ww.x, 0.f); sn.x += fmaxf(-ww.x, 0.f);
            sp.y += fmaxf(ww.y, 0.f); sn.y += fmaxf(-ww.y, 0.f);
            sp.z += fmaxf(ww.z, 0.f); sn.z += fmaxf(-ww.z, 0.f);
            sp.w += fmaxf(ww.w, 0.f); sn.w += fmaxf(-ww.w, 0.f);
        }
        redPt[(c4 + 0) * 129 + rg] = sp.x; redNt[(c4 + 0) * 129 + rg] = sn.x;
        redPt[(c4 + 1) * 129 + rg] = sp.y; redNt[(c4 + 1) * 129 + rg] = sn.y;
        redPt[(c4 + 2) * 129 + rg] = sp.z; redNt[(c4 + 2) * 129 + rg] = sn.z;
        redPt[(c4 + 3) * 129 + rg] = sp.w; redNt[(c4 + 3) * 129 + rg] = sn.w;
        __syncthreads();
        if (tid < 64) {
            int cc = tid & 31;
            const float* rp = (tid < 32) ? redPt : redNt;
            float t = 0.f;
#pragma unroll 8
            for (int g = 0; g < 128; ++g) t += rp[cc * 129 + g];
            scol[(tid >> 5) * 32 + cc] = t;
        }
        __syncthreads();
        if (tid < 32 * E) {
            int cc = tid / E, f = tid % E;
            float spc = scol[cc], snc = scol[32 + cc];
            float acc = features[(b << 10) + i0 + cc] * w_sel[f];
#pragma unroll
            for (int e = 0; e < E; ++e) {
                float ce = w_ew[e];
                float se = (ce > 0.f) ? ce * spc : (-ce) * snc;
                acc += w_nbw[f * E + e] * se;
            }
            b_reg = acc;
            int row = i0 + cc;
            store_llc(&eA[(size_t)b * EMB_FLOATS + (row >> 2) * GP + (row & 3) * E + f],
                      fmaxf(acc, 0.f));
        }
    }
    batch_barrier(&mybars[0]);

    // ---- 4 remaining reference iterations, A tile register-resident ----
    float da = 0.f;
    for (int it = 0; it < 4; ++it) {
        const float* ein = (it & 1) ? (const float*)eB : (const float*)eA;
        float* eout = (it & 1) ? eA : eB;

        // stage whole-batch emb: 3 LLC-bypass float4 loads/thread, ds_writes
        {
            const f32x4* src = (const f32x4*)ein + (size_t)b * EMB_F4;
            f32x4 t0, t1, t2 = {0.f, 0.f, 0.f, 0.f};
            asm volatile("global_load_dwordx4 %0, %1, off sc0 sc1"
                         : "=v"(t0) : "v"(src + tid) : "memory");
            asm volatile("global_load_dwordx4 %0, %1, off sc0 sc1"
                         : "=v"(t1) : "v"(src + tid + 1024) : "memory");
            if (tid < EMB_F4 - 2048)
                asm volatile("global_load_dwordx4 %0, %1, off sc0 sc1"
                             : "=v"(t2) : "v"(src + tid + 2048) : "memory");
            asm volatile("s_waitcnt vmcnt(0)" ::: "memory");
            __builtin_amdgcn_sched_barrier(0);
            ((f32x4*)EmS)[tid]        = t0;
            ((f32x4*)EmS)[tid + 1024] = t1;
            if (tid < EMB_F4 - 2048) ((f32x4*)EmS)[tid + 2048] = t2;
        }
        __syncthreads();

        float acc[2][E];
#pragma unroll
        for (int k = 0; k < 2; ++k)
#pragma unroll
            for (int e = 0; e < E; ++e) acc[k][e] = 0.f;

#pragma unroll
        for (int c = 0; c < 4; ++c) {
            float4 g4[10];
            const float4* gp = EmS + (size_t)(s + 64 * c) * (GP / 4);
#pragma unroll
            for (int t = 0; t < 10; ++t) g4[t] = gp[t];
            const float* g40 = (const float*)g4;
#pragma unroll
            for (int q = 0; q < 4; ++q)
#pragma unroll
                for (int k = 0; k < 2; ++k) {
                    float a = Arf[k][c][q];
#pragma unroll
                    for (int e = 0; e < E; ++e)
                        acc[k][e] += a * g40[q * E + e];
                }
        }

        // full 64-lane reduction in-register (VALU DPP); lane 63 holds
        // complete v[row][e] for this wave's two rows -> 5 packed writes.
#pragma unroll
        for (int k = 0; k < 2; ++k)
#pragma unroll
            for (int e = 0; e < E; ++e) {
                float x = acc[k][e];
                DPP_REDUCE64(x);
                acc[k][e] = x;
            }
        if (s == 63) {
            float4* vp = (float4*)&vred[m][0];
            vp[0] = make_float4(acc[0][0], acc[0][1], acc[0][2], acc[0][3]);
            vp[1] = make_float4(acc[0][4], acc[0][5], acc[0][6], acc[0][7]);
            vp[2] = make_float4(acc[0][8], acc[0][9], acc[1][0], acc[1][1]);
            vp[3] = make_float4(acc[1][2], acc[1][3], acc[1][4], acc[1][5]);
            vp[4] = make_float4(acc[1][6], acc[1][7], acc[1][8], acc[1][9]);
        }
        __syncthreads();

        if (tid < 32 * E) {
            int r = tid / E, f = tid % E;
            const float* v = &vred[r & 15][(r >> 4) * E];   // 10-lane broadcast
            float d = 0.f;
#pragma unroll
            for (int e = 0; e < E; ++e) d += v[e] * WpS[f * E + e];
            float r_out = fmaxf(b_reg + d, 0.f);
            if (it < 3) {
                int grow = i0 + r;
                store_llc(&eout[(size_t)b * EMB_FLOATS + (grow >> 2) * GP + (grow & 3) * E + f],
                          r_out);
            } else {
                size_t gi = (size_t)((b << 10) + i0 + r);
                emb_out[gi * E + f] = r_out;
                vS[tid] = r_out * gactS[f];
                qS[tid] = r_out * gaS[f];
            }
        }
        if (it < 3) batch_barrier(&mybars[(1 + it) * B * BAR_PAD]);
    }

    // ---- q epilogue: per-tile partials, one barrier, deterministic sum ----
    __syncthreads();
    if (tid < 32) {
        float dg = 0.f;
#pragma unroll
        for (int f = 0; f < E; ++f) {
            da += vS[tid * E + f];
            dg += qS[tid * E + f];
        }
        qrow[tid] = dg;
    }
    __syncthreads();
    if (tid == 0) {
        float t = 0.f;
#pragma unroll
        for (int r = 0; r < 32; ++r) t += qrow[r];
        store_llc(&qpart[bx], t);
    }
    batch_barrier(&mybars[4 * B * BAR_PAD]);

    if (tid < 32) {
        float t = load_llc(&qpart[(b << 5) + tid]);
#pragma unroll
        for (int mask = 1; mask < 32; mask <<= 1)
            t += __shfl_xor(t, mask, 32);
        if (tid == 0) qsumS = t;
    }
    __syncthreads();
    if (tid < 32) qv[(b << 10) + i0 + tid] = da + qsumS;
}

extern "C" void kernel_launch(void* const* d_in, const int* in_sizes, int n_in,
                              void* d_out, int out_size, void* d_ws, size_t ws_size,
                              hipStream_t stream) {
    const float* features  = (const float*)d_in[0];
    const float* W         = (const float*)d_in[1];
    const float* adjacency = (const float*)d_in[2];
    const float* w_sel     = (const float*)d_in[3];
    const float* w_pri     = (const float*)d_in[4];
    const float* w_nbw     = (const float*)d_in[5];
    const float* w_ew      = (const float*)d_in[6];
    const float* w_reduc   = (const float*)d_in[7];
    const float* w_all     = (const float*)d_in[8];
    const float* w_act     = (const float*)d_in[9];

    float* out     = (float*)d_out;
    float* qv      = out;              // B*N
    float* emb_out = out + B * N;      // B*N*E

    float* ws      = (float*)d_ws;
    float* eA      = ws;                               // B*EMB_FLOATS
    float* eB      = eA + (size_t)B * EMB_FLOATS;
    float* qpart   = eB + (size_t)B * EMB_FLOATS;      // 256 floats
    unsigned* bars = (unsigned*)(qpart + NBLK);        // 5 stages x 8 batches x 128B

    hipMemsetAsync(bars, 0, 5 * B * BAR_PAD * sizeof(unsigned), stream);
    k_fused10<<<NBLK, 1024, 0, stream>>>(W, features, w_sel, w_nbw, w_ew,
                                         adjacency, w_pri, w_reduc, w_all,
                                         w_act, eA, eB, emb_out, qv, qpart,
                                         bars);
}